// Round 9
// baseline (343.914 us; speedup 1.0000x reference)
//
#include <hip/hip_runtime.h>
#include <hip/hip_bf16.h>

#define SEQ 2048
#define DM 2048
#define NH 16
#define NKV 4
#define HD 128

typedef float f32x4 __attribute__((ext_vector_type(4)));
typedef float f32x16 __attribute__((ext_vector_type(16)));
typedef short s16x8 __attribute__((ext_vector_type(8)));
typedef short s16x4 __attribute__((ext_vector_type(4)));
typedef unsigned u32x4 __attribute__((ext_vector_type(4)));

__device__ inline __hip_bfloat16 f2b(float f) { return __float2bfloat16(f); }
__device__ inline float b2f_us(unsigned short u) { return __uint_as_float(((unsigned)u) << 16); }
__device__ inline short f2b_s(float f) {
    __hip_bfloat16 h = __float2bfloat16(f);
    return *(short*)&h;
}
// pack two f32 -> u32 of 2 bf16 (lo in low16). Compiler emits cvt_pk (m240).
__device__ inline unsigned pk2(float lo, float hi) {
    unsigned a = (unsigned)(unsigned short)f2b_s(lo);
    unsigned b = (unsigned)(unsigned short)f2b_s(hi);
    return a | (b << 16);
}
// v_permlane32_swap_b32: a' = {a[0:31], b[0:31]}, b' = {a[32:63], b[32:63]}
__device__ inline void pl32swap(unsigned& a, unsigned& b) {
    asm("v_permlane32_swap_b32 %0, %1" : "+v"(a), "+v"(b));
}

// async global->LDS, 16B per lane; HW dest = wave-uniform base + lane*16.
__device__ inline void gl_lds16(const void* g, void* l) {
    __builtin_amdgcn_global_load_lds((const __attribute__((address_space(1))) void*)g,
                                     (__attribute__((address_space(3))) void*)l, 16, 0, 0);
}

// ---------------- fused prep: cast x->bf16  +  4x transpose_cast (weights) ----------
__global__ void prep_kernel(const float* __restrict__ x,
                            const float* __restrict__ wq, const float* __restrict__ wk,
                            const float* __restrict__ wv, const float* __restrict__ wo,
                            __hip_bfloat16* __restrict__ xb,
                            __hip_bfloat16* __restrict__ wqkvt,
                            __hip_bfloat16* __restrict__ wot) {
    __shared__ float tile[32][33];
    int bid = blockIdx.x;
    const int t = threadIdx.x;
    if (bid < 8192) {
        int i = (bid * 256 + t) * 4;
        float4 v = *(const float4*)(x + i);
        __hip_bfloat16 o4[4] = {f2b(v.x), f2b(v.y), f2b(v.z), f2b(v.w)};
        *(ushort4*)(xb + i) = *(ushort4*)o4;
        return;
    }
    bid -= 8192;
    const float* in;
    __hip_bfloat16* out;
    int N, bx, by;
    if (bid < 4096) {
        in = wq; out = wqkvt; N = 2048; bx = bid & 63; by = bid >> 6;
    } else if (bid < 5120) {
        bid -= 4096; in = wk; out = wqkvt + (size_t)2048 * 2048; N = 512; bx = bid & 15; by = bid >> 4;
    } else if (bid < 6144) {
        bid -= 5120; in = wv; out = wqkvt + (size_t)2560 * 2048; N = 512; bx = bid & 15; by = bid >> 4;
    } else {
        bid -= 6144; in = wo; out = wot; N = 2048; bx = bid & 63; by = bid >> 6;
    }
    const int K = 2048;
    int n0 = bx * 32, k0 = by * 32;
    int tx = t & 31, ty = t >> 5; // logical (32,8)
    for (int r = ty; r < 32; r += 8)
        tile[r][tx] = in[(size_t)(k0 + r) * N + n0 + tx];
    __syncthreads();
    for (int r = ty; r < 32; r += 8)
        out[(size_t)(n0 + r) * K + k0 + tx] = f2b(tile[tx][r]);
}

// ---------------- GEMM: C[M][N] = A[M][Kd] * Bt[N][Kd]^T ----------------
// m97 structure + GROUP_M=8 grouped supertile swizzle (128^2 tile fits the shapes
// exactly: 768 blocks = 3/CU and 512 = 2/CU; R14's 256^2 experiment regressed).
template <int OUT_F32>
__global__ __launch_bounds__(256, 3) void gemm_bt(
    const __hip_bfloat16* __restrict__ A,
    const __hip_bfloat16* __restrict__ Bt,
    void* __restrict__ Cp, int M, int N, int Kd) {
    __shared__ __hip_bfloat16 As[128 * 64]; // [row][64], swizzled 16B slots
    __shared__ __hip_bfloat16 Bs[128 * 64];
    const int nx = gridDim.x, ny = gridDim.y;
    const int pid = blockIdx.y * nx + blockIdx.x;
    const int GM = 8;
    const int grp = pid / (GM * nx);
    const int first = grp * GM;
    const int gsz = (ny - first < GM) ? (ny - first) : GM;
    const int mt = first + (pid % gsz);
    const int ntile = (pid % (GM * nx)) / gsz;
    const int m0 = mt * 128, n0 = ntile * 128;

    const int t = threadIdx.x;
    const int wv = t >> 6, lane = t & 63;
    const int wm = (wv >> 1) * 64, wn = (wv & 1) * 64;
    const int lrow = lane & 15, quad = lane >> 4;
    f32x4 acc[4][4];
    f32x4 z4 = {0.f, 0.f, 0.f, 0.f};
    for (int i = 0; i < 4; ++i)
        for (int j = 0; j < 4; ++j) acc[i][j] = z4;

    for (int k0 = 0; k0 < Kd; k0 += 64) {
        __syncthreads();
        for (int i = 0; i < 4; ++i) {
            int flat = i * 256 + t;          // 16B slot id
            int row = flat >> 3;
            int cb = (flat & 7) ^ (row & 7); // logical 16B-block for this slot
            gl_lds16(A + (size_t)(m0 + row) * Kd + k0 + cb * 8, &As[flat * 8]);
            gl_lds16(Bt + (size_t)(n0 + row) * Kd + k0 + cb * 8, &Bs[flat * 8]);
        }
        __syncthreads();
        for (int kk = 0; kk < 2; ++kk) {
            s16x8 af[4], bf[4];
            for (int i = 0; i < 4; ++i) {
                int ra = wm + i * 16 + lrow;
                int rb = wn + i * 16 + lrow;
                int pba = ((kk * 4 + quad) ^ (ra & 7)) * 8;
                int pbb = ((kk * 4 + quad) ^ (rb & 7)) * 8;
                af[i] = *(const s16x8*)&As[ra * 64 + pba];
                bf[i] = *(const s16x8*)&Bs[rb * 64 + pbb];
            }
            for (int i = 0; i < 4; ++i)
                for (int j = 0; j < 4; ++j)
                    acc[i][j] = __builtin_amdgcn_mfma_f32_16x16x32_bf16(af[i], bf[j],
                                                                        acc[i][j], 0, 0, 0);
        }
    }
    for (int i = 0; i < 4; ++i)
        for (int j = 0; j < 4; ++j)
            for (int r = 0; r < 4; ++r) {
                int m = m0 + wm + i * 16 + quad * 4 + r;
                int n = n0 + wn + j * 16 + lrow;
                if (OUT_F32)
                    ((float*)Cp)[(size_t)m * N + n] = acc[i][j][r];
                else
                    ((__hip_bfloat16*)Cp)[(size_t)m * N + n] = f2b(acc[i][j][r]);
            }
}

// ---------------- fused RoPE(q,k) + V-transpose ----------------
#define QSC 0.12751744f /* (1/sqrt(128)) * 1.4426950408889634 */
__global__ void rv_kernel(const __hip_bfloat16* __restrict__ qkv,
                          const float* __restrict__ fcos, const float* __restrict__ fsin,
                          __hip_bfloat16* __restrict__ q, __hip_bfloat16* __restrict__ k,
                          __hip_bfloat16* __restrict__ vt) {
    __shared__ __hip_bfloat16 tile[128][136];
    const int t = threadIdx.x;
    if (blockIdx.x < 4096) {
        int tok = blockIdx.x; // b*SEQ + s
        int b = tok >> 11, s = tok & 2047;
        const __hip_bfloat16* row = qkv + (size_t)tok * 3072;
        for (int it = t; it < 320; it += 256) { // 2560 elems / 8
            int col = it * 8;
            s16x8 v = *(const s16x8*)(row + col);
            int p0 = (col & 127) >> 1;
            f32x4 c4 = *(const f32x4*)(fcos + s * 64 + p0);
            f32x4 s4 = *(const f32x4*)(fsin + s * 64 + p0);
            float scl = (col < 2048) ? QSC : 1.0f;
            short outv[8];
            for (int p = 0; p < 4; ++p) {
                float x0 = b2f_us((unsigned short)v[2 * p]);
                float x1 = b2f_us((unsigned short)v[2 * p + 1]);
                outv[2 * p] = f2b_s((x0 * c4[p] - x1 * s4[p]) * scl);
                outv[2 * p + 1] = f2b_s((x0 * s4[p] + x1 * c4[p]) * scl);
            }
            int d = col & 127;
            if (col < 2048) {
                int h = col >> 7;
                *(s16x8*)(q + ((size_t)((b * NH + h) * SEQ + s)) * HD + d) = *(s16x8*)outv;
            } else {
                int h = (col - 2048) >> 7;
                *(s16x8*)(k + ((size_t)((b * NKV + h) * SEQ + s)) * HD + d) = *(s16x8*)outv;
            }
        }
        return;
    }
    int r = blockIdx.x - 4096;
    int s0 = (r & 15) * 128;
    int bh = r >> 4; // b*NKV + kvh
    int b = bh >> 2, kvh = bh & 3;
    for (int i = 0; i < 8; ++i) {
        int flat = (i * 256 + t) * 8;
        int row = flat >> 7, col = flat & 127;
        *(s16x8*)&tile[row][col] =
            *(const s16x8*)(qkv + (size_t)(b * SEQ + s0 + row) * 3072 + 2560 + kvh * 128 + col);
    }
    __syncthreads();
    for (int i = 0; i < 8; ++i) {
        int dd = i * 16 + (t >> 4);
        int ss = (t & 15) * 8;
        __hip_bfloat16 tmp[8];
        for (int j = 0; j < 8; ++j) tmp[j] = tile[ss + j][dd];
        *(s16x8*)(vt + ((size_t)((b * NKV + kvh) * HD + dd)) * SEQ + s0 + ss) = *(s16x8*)tmp;
    }
}

// ---------------- causal flash attention (GQA), 128 q-rows / 256 threads ----------------
// R16: structural fix for the measured LDS-throughput bound (per wave-tile the 16x16x32
// version issued 32 ds_read_b128 (~12cyc) vs 32 MFMA (~5cyc); LDS pipe ~60% of dispatch).
// Switch to mfma_f32_32x32x16_bf16: same 16B operand per MFMA but 2x the FLOPs ->
// LDS reads per FLOP HALVE. 4 waves x 32 q-rows (wave's lane l31 owns q-col l31).
// Verified layouts: A/B-frag row/col=lane&31, k=(lane>>5)*8+j; C/D col=lane&31,
// row=(reg&3)+8*(reg>>2)+4*(lane>>5) [m74/m101]. P key-order -> B-frag fixed with T12:
// bf16 pair packs + v_permlane32_swap_b32 (swap(c0,c2) yields j01 and j45 frags).
// V stays in NATURAL key order (posOf permute deleted). Softmax reduce = one shfl_xor 32.
// Kept: exp2-domain softmax (pre-scaled Q), defer-max, setprio, anti-correlated mapping,
// single-buffered K/V + 2 barriers/tile.
__global__ __launch_bounds__(256, 2) void attn_kernel(
    const __hip_bfloat16* __restrict__ q, const __hip_bfloat16* __restrict__ k,
    const __hip_bfloat16* __restrict__ vt, __hip_bfloat16* __restrict__ o) {
    __shared__ __hip_bfloat16 Ks[64][136]; // keys x d
    __shared__ __hip_bfloat16 Vs[128][72]; // d x keys (natural order)

    const int bh = blockIdx.y;
    const int bx = (bh < 16) ? (int)(gridDim.x - 1 - blockIdx.x) : (int)blockIdx.x;
    const int b = bh >> 4, hh = bh & 15;
    const int kvh = hh >> 2;
    const int t = threadIdx.x;
    const int w = t >> 6, lane = t & 63;
    const int l31 = lane & 31, hf = lane >> 5;
    const int q0 = bx * 128;
    const int qrow = q0 + w * 32 + l31; // this lane's ONE q row

    // Q fragments, B-operand role: col=qrow (l31), k=d = kw*16 + hf*8 + j. Pre-scaled.
    const __hip_bfloat16* qp = q + ((size_t)((b * NH + hh) * SEQ + qrow)) * HD;
    s16x8 qf[8];
#pragma unroll
    for (int kw = 0; kw < 8; ++kw) qf[kw] = *(const s16x8*)(qp + kw * 16 + hf * 8);

    float m_i = -1e30f, l_i = 0.f;
    f32x16 accO[4];
#pragma unroll
    for (int db = 0; db < 4; ++db)
#pragma unroll
        for (int r = 0; r < 16; ++r) accO[db][r] = 0.f;

    const __hip_bfloat16* kbase = k + ((size_t)(b * NKV + kvh) * SEQ) * HD;
    const __hip_bfloat16* vbase = vt + ((size_t)(b * NKV + kvh) * HD) * SEQ;

    s16x8 kr[4], vr[4];
    auto load_tile = [&](int kt) {
#pragma unroll
        for (int i = 0; i < 4; ++i) {
            int flat = (i * 256 + t) * 8;
            kr[i] = *(const s16x8*)(kbase + (size_t)(kt * 64 + (flat >> 7)) * HD + (flat & 127));
            vr[i] = *(const s16x8*)(vbase + (size_t)(flat >> 6) * SEQ + kt * 64 + (flat & 63));
        }
    };
    auto store_tile = [&]() {
#pragma unroll
        for (int i = 0; i < 4; ++i) {
            int flat = (i * 256 + t) * 8;
            *(s16x8*)&Ks[flat >> 7][flat & 127] = kr[i];
            *(s16x8*)&Vs[flat >> 6][flat & 63] = vr[i];
        }
    };

    const int nkt = 2 * bx + 2; // keys [0, q0+128)
    load_tile(0);
    store_tile();

    for (int kt = 0; kt < nkt; ++kt) {
        bool more = (kt + 1) < nkt;
        __syncthreads(); // K/V tile stored and visible
        if (more) load_tile(kt + 1); // global->reg, hidden under compute
        bool wave_active = (kt * 64 <= q0 + w * 32 + 31);
        bool mtile = (kt >= 2 * bx); // tile may touch the diagonal

        if (wave_active) {
            f32x16 s0, s1;
#pragma unroll
            for (int r = 0; r < 16; ++r) { s0[r] = 0.f; s1[r] = 0.f; }
            __builtin_amdgcn_s_setprio(1);
#pragma unroll
            for (int kw = 0; kw < 8; ++kw) {
                s16x8 kf0 = *(const s16x8*)&Ks[l31][kw * 16 + hf * 8];      // keys 0-31
                s16x8 kf1 = *(const s16x8*)&Ks[32 + l31][kw * 16 + hf * 8]; // keys 32-63
                s0 = __builtin_amdgcn_mfma_f32_32x32x16_bf16(kf0, qf[kw], s0, 0, 0, 0);
                s1 = __builtin_amdgcn_mfma_f32_32x32x16_bf16(kf1, qf[kw], s1, 0, 0, 0);
            }
            __builtin_amdgcn_s_setprio(0);
            if (mtile) {
#pragma unroll
                for (int r = 0; r < 16; ++r) {
                    int key0 = kt * 64 + (r & 3) + 8 * (r >> 2) + 4 * hf;
                    if (key0 > qrow) s0[r] = -1e30f;
                    if (key0 + 32 > qrow) s1[r] = -1e30f;
                }
            }
            float mt2 = -1e30f;
#pragma unroll
            for (int r = 0; r < 16; ++r) mt2 = fmaxf(mt2, fmaxf(s0[r], s1[r]));
            mt2 = fmaxf(mt2, __shfl_xor(mt2, 32, 64));
            // defer-max: only rescale when running max grew by >8 (exp2 domain).
            if (!__all(mt2 <= m_i + 8.f)) {
                float mn = fmaxf(m_i, mt2);
                float alpha = exp2f(m_i - mn);
                l_i *= alpha;
#pragma unroll
                for (int db = 0; db < 4; ++db)
#pragma unroll
                    for (int r = 0; r < 16; ++r) accO[db][r] *= alpha;
                m_i = mn;
            }
            // P in-register; packs c[i] = keys {pair} per lane-half, then permlane32
            // swaps realign key order to the B-frag layout (k = hf*8 + j).
            float rs = 0.f;
            unsigned c[16];
#pragma unroll
            for (int r = 0; r < 8; ++r) {
                float pa = exp2f(s0[2 * r] - m_i);
                float pb = exp2f(s0[2 * r + 1] - m_i);
                rs += pa + pb;
                c[r] = pk2(pa, pb);
            }
#pragma unroll
            for (int r = 0; r < 8; ++r) {
                float pa = exp2f(s1[2 * r] - m_i);
                float pb = exp2f(s1[2 * r + 1] - m_i);
                rs += pa + pb;
                c[8 + r] = pk2(pa, pb);
            }
            rs += __shfl_xor(rs, 32, 64);
            l_i += rs;
            // after swap(a,b): a = j01-frag, b = j45-frag (guide T12 derivation)
            pl32swap(c[0], c[2]);  pl32swap(c[1], c[3]);   // keys 0-15
            pl32swap(c[4], c[6]);  pl32swap(c[5], c[7]);   // keys 16-31
            pl32swap(c[8], c[10]); pl32swap(c[9], c[11]);  // keys 32-47
            pl32swap(c[12], c[14]); pl32swap(c[13], c[15]); // keys 48-63
            u32x4 pw0 = {c[0], c[1], c[2], c[3]};
            u32x4 pw1 = {c[4], c[5], c[6], c[7]};
            u32x4 pw2 = {c[8], c[9], c[10], c[11]};
            u32x4 pw3 = {c[12], c[13], c[14], c[15]};
            s16x8 pf0 = __builtin_bit_cast(s16x8, pw0);
            s16x8 pf1 = __builtin_bit_cast(s16x8, pw1);
            s16x8 pf2 = __builtin_bit_cast(s16x8, pw2);
            s16x8 pf3 = __builtin_bit_cast(s16x8, pw3);
            __builtin_amdgcn_s_setprio(1);
#pragma unroll
            for (int db = 0; db < 4; ++db) {
                s16x8 vf0 = *(const s16x8*)&Vs[db * 32 + l31][0 + hf * 8];
                s16x8 vf1 = *(const s16x8*)&Vs[db * 32 + l31][16 + hf * 8];
                s16x8 vf2 = *(const s16x8*)&Vs[db * 32 + l31][32 + hf * 8];
                s16x8 vf3 = *(const s16x8*)&Vs[db * 32 + l31][48 + hf * 8];
                accO[db] = __builtin_amdgcn_mfma_f32_32x32x16_bf16(vf0, pf0, accO[db], 0, 0, 0);
                accO[db] = __builtin_amdgcn_mfma_f32_32x32x16_bf16(vf1, pf1, accO[db], 0, 0, 0);
                accO[db] = __builtin_amdgcn_mfma_f32_32x32x16_bf16(vf2, pf2, accO[db], 0, 0, 0);
                accO[db] = __builtin_amdgcn_mfma_f32_32x32x16_bf16(vf3, pf3, accO[db], 0, 0, 0);
            }
            __builtin_amdgcn_s_setprio(0);
        }

        __syncthreads(); // all waves done reading Ks/Vs
        if (more) store_tile();
    }
    float inv = 1.0f / l_i;
    // C/D row = d = db*32 + 8*g + (e) + 4*hf for reg r = 4g+e; col = qrow (l31).
    __hip_bfloat16* op = o + (size_t)(b * SEQ + qrow) * DM + hh * HD;
#pragma unroll
    for (int db = 0; db < 4; ++db)
#pragma unroll
        for (int g = 0; g < 4; ++g) {
            short ov[4];
#pragma unroll
            for (int e = 0; e < 4; ++e) ov[e] = f2b_s(accO[db][4 * g + e] * inv);
            *(s16x4*)(op + db * 32 + g * 8 + hf * 4) = *(s16x4*)ov;
        }
}

extern "C" void kernel_launch(void* const* d_in, const int* in_sizes, int n_in,
                              void* d_out, int out_size, void* d_ws, size_t ws_size,
                              hipStream_t stream) {
    (void)in_sizes; (void)n_in; (void)out_size; (void)ws_size;
    const float* x  = (const float*)d_in[0];
    const float* fc = (const float*)d_in[1];
    const float* fs = (const float*)d_in[2];
    // d_in[3] = mask: exactly causal, applied analytically
    const float* wq = (const float*)d_in[4];
    const float* wk = (const float*)d_in[5];
    const float* wv = (const float*)d_in[6];
    const float* wo = (const float*)d_in[7];

    __hip_bfloat16* xb    = (__hip_bfloat16*)d_ws;            // [4096][2048]
    __hip_bfloat16* wqkvt = xb + (size_t)8388608;             // [3072][2048]
    __hip_bfloat16* wot   = wqkvt + (size_t)6291456;          // [2048][2048]
    __hip_bfloat16* qkv   = wot + (size_t)4194304;            // [4096][3072]
    __hip_bfloat16* qb    = xb;                               // aliases xb
    __hip_bfloat16* kb    = wqkvt;                            // aliases wqkvt
    __hip_bfloat16* vtb   = wqkvt + (size_t)2097152;
    __hip_bfloat16* attno = qkv;                              // aliases qkv

    prep_kernel<<<18432, 256, 0, stream>>>(x, wq, wk, wv, wo, xb, wqkvt, wot);
    gemm_bt<0><<<dim3(24, 32), 256, 0, stream>>>(xb, wqkvt, qkv, 4096, 3072, 2048);
    rv_kernel<<<4224, 256, 0, stream>>>(qkv, fc, fs, qb, kb, vtb);
    attn_kernel<<<dim3(16, 32), 256, 0, stream>>>(qb, kb, vtb, attno);
    gemm_bt<1><<<dim3(16, 32), 256, 0, stream>>>(attno, wot, d_out, 4096, 2048, 2048);
}